// Round 1
// baseline (1334.343 us; speedup 1.0000x reference)
//
#include <hip/hip_runtime.h>
#include <hip/hip_bf16.h>

// BiomarkerGNN: N=100000 nodes, E=1200000 edges, F=128, HID=64, PROJ=32.
// Pipeline:
//   deg (int atomics) -> dinv=rsqrt(deg+1)
//   fused GEMM128: h_mlp = relu(BN(x@W1+b1));  hw0_s = (x@gW0)*dinv[row]; agg0 = hw0_s*dinv[row]
//   scatter: agg[dst] += hw_s[src]*dinv[dst]   (f32 global atomics)
//   finalize: hg = relu(agg + b)
//   gemm64 (x2 layers), scatter, finalize
//   head: gate/fuse/proj/classifier, one wave (64 lanes) per node, shuffle-based GEMVs
//
// Workspace layout (floats), total 258*N*4B ~= 103.2 MB:
//   [0,N)      deg (as int)
//   [N,2N)     dinv
//   [2N,66N)   h_mlp
//   [66N,130N) bufA (hw_scaled)
//   [130N,194N) bufB (agg)
//   [194N,258N) bufC (hg)

#define HID 64

__global__ __launch_bounds__(256) void deg_kernel(const int* __restrict__ dst, int E,
                                                  int* __restrict__ deg) {
    int e = blockIdx.x * 256 + threadIdx.x;
    if (e < E) atomicAdd(&deg[dst[e]], 1);
}

__global__ __launch_bounds__(256) void dinv_kernel(const int* __restrict__ deg,
                                                   float* __restrict__ dinv, int N) {
    int i = blockIdx.x * 256 + threadIdx.x;
    if (i < N) dinv[i] = rsqrtf((float)deg[i] + 1.0f);  // +1 = self loop
}

// 4 rows/block, 64 cols. Computes both MLP branch (W1+BN+relu) and GCN layer-0 matmul.
__global__ __launch_bounds__(256) void gemm128_fused(
    const float* __restrict__ x,
    const float* __restrict__ W1, const float* __restrict__ b1,
    const float* __restrict__ gamma, const float* __restrict__ beta,
    const float* __restrict__ rmean, const float* __restrict__ rvar,
    const float* __restrict__ gW0,
    const float* __restrict__ dinv,
    float* __restrict__ h_mlp, float* __restrict__ hw_s, float* __restrict__ agg,
    int N) {
    __shared__ float sx[4][128];
    int tid = threadIdx.x;
    int rblk = blockIdx.x * 4;
    // cooperative load of 4 input rows (512 floats, 2 per thread, coalesced)
    for (int i = tid; i < 512; i += 256) {
        int r = i >> 7, k = i & 127;
        int row = rblk + r;
        sx[r][k] = (row < N) ? x[(size_t)row * 128 + k] : 0.0f;
    }
    __syncthreads();
    int r = tid >> 6, c = tid & 63;
    int row = rblk + r;
    if (row >= N) return;
    float acc1 = 0.f, acc2 = 0.f;
#pragma unroll 8
    for (int k = 0; k < 128; ++k) {
        float xv = sx[r][k];
        acc1 = fmaf(xv, W1[k * HID + c], acc1);
        acc2 = fmaf(xv, gW0[k * HID + c], acc2);
    }
    // BatchNorm (eval) + relu
    float h = (acc1 + b1[c] - rmean[c]) * rsqrtf(rvar[c] + 1e-5f) * gamma[c] + beta[c];
    h_mlp[(size_t)row * HID + c] = fmaxf(h, 0.f);
    float dv = dinv[row];
    float hs = acc2 * dv;                      // pre-scale by dinv[src]
    hw_s[(size_t)row * HID + c] = hs;
    agg[(size_t)row * HID + c] = hs * dv;      // self-loop contribution
}

// 64x64 GEMM for GCN layers 1,2. Input hin [N,64], weight W [64,64].
__global__ __launch_bounds__(256) void gemm64_layer(
    const float* __restrict__ hin, const float* __restrict__ W,
    const float* __restrict__ dinv,
    float* __restrict__ hw_s, float* __restrict__ agg, int N) {
    __shared__ float sx[4][64];
    int tid = threadIdx.x;
    int rblk = blockIdx.x * 4;
    {
        int r = tid >> 6, k = tid & 63;
        int row = rblk + r;
        sx[r][k] = (row < N) ? hin[(size_t)row * HID + k] : 0.f;
    }
    __syncthreads();
    int r = tid >> 6, c = tid & 63;
    int row = rblk + r;
    if (row >= N) return;
    float acc = 0.f;
#pragma unroll 8
    for (int k = 0; k < 64; ++k)
        acc = fmaf(sx[r][k], W[k * HID + c], acc);
    float dv = dinv[row];
    float hs = acc * dv;
    hw_s[(size_t)row * HID + c] = hs;
    agg[(size_t)row * HID + c] = hs * dv;
}

// 4 edges/block, 64 cols each. agg[dst] += hw_s[src] * dinv[dst]
__global__ __launch_bounds__(256) void scatter_kernel(
    const int* __restrict__ src, const int* __restrict__ dst,
    const float* __restrict__ hw_s, const float* __restrict__ dinv,
    float* __restrict__ agg, int E) {
    int tid = threadIdx.x;
    int e = blockIdx.x * 4 + (tid >> 6);
    if (e >= E) return;
    int c = tid & 63;
    int s = src[e], d = dst[e];
    float val = hw_s[(size_t)s * HID + c] * dinv[d];
    atomicAdd(&agg[(size_t)d * HID + c], val);
}

__global__ __launch_bounds__(256) void finalize_kernel(
    const float* __restrict__ agg, const float* __restrict__ b,
    float* __restrict__ hg, int N64) {
    int i = blockIdx.x * 256 + threadIdx.x;
    if (i < N64) {
        int c = i & 63;
        hg[i] = fmaxf(agg[i] + b[c], 0.f);
    }
}

// One wave (64 lanes) per node; 4 nodes per 256-thread block. No LDS (shuffle bcast).
__global__ __launch_bounds__(256) void head_kernel(
    const float* __restrict__ h_mlp, const float* __restrict__ hg,
    const float* __restrict__ gateW, const float* __restrict__ gateb,
    const float* __restrict__ pW1, const float* __restrict__ pb1,
    const float* __restrict__ pW2, const float* __restrict__ pb2,
    const float* __restrict__ cW, const float* __restrict__ cb,
    float* __restrict__ logits, float* __restrict__ zproj, int N) {
    int tid = threadIdx.x;
    int lane = tid & 63;
    int node = blockIdx.x * 4 + (tid >> 6);
    if (node >= N) return;
    float hm = h_mlp[(size_t)node * HID + lane];
    float hv = hg[(size_t)node * HID + lane];
    // gate = sigmoid([h_mlp, hg] @ gateW + gateb)
    float p = fmaf(hm, gateW[lane], hv * gateW[64 + lane]);
#pragma unroll
    for (int m = 32; m >= 1; m >>= 1) p += __shfl_xor(p, m, 64);
    float gate = 1.f / (1.f + expf(-(p + gateb[0])));
    float hf = gate * hv + (1.f - gate) * hm;
    // t = relu(h_fused @ pW1 + pb1)  via shuffle broadcast of hf
    float t = pb1[lane];
#pragma unroll 8
    for (int c0 = 0; c0 < 64; ++c0) {
        float hfc = __shfl(hf, c0, 64);
        t = fmaf(hfc, pW1[c0 * HID + lane], t);
    }
    t = fmaxf(t, 0.f);
    // z = t @ pW2 + pb2 (first 32 lanes write)
    float z = (lane < 32) ? pb2[lane] : 0.f;
#pragma unroll 8
    for (int c0 = 0; c0 < 64; ++c0) {
        float tc = __shfl(t, c0, 64);
        if (lane < 32) z = fmaf(tc, pW2[c0 * 32 + lane], z);
    }
    if (lane < 32) zproj[(size_t)node * 32 + lane] = z;
    // logit = h_fused @ cW + cb
    float q = hf * cW[lane];
#pragma unroll
    for (int m = 32; m >= 1; m >>= 1) q += __shfl_xor(q, m, 64);
    if (lane == 0) logits[node] = q + cb[0];
}

extern "C" void kernel_launch(void* const* d_in, const int* in_sizes, int n_in,
                              void* d_out, int out_size, void* d_ws, size_t ws_size,
                              hipStream_t stream) {
    const float* x     = (const float*)d_in[0];
    const int*   edge  = (const int*)d_in[1];
    const float* W1    = (const float*)d_in[2];
    const float* b1    = (const float*)d_in[3];
    const float* gamma = (const float*)d_in[4];
    const float* beta  = (const float*)d_in[5];
    const float* rmean = (const float*)d_in[6];
    const float* rvar  = (const float*)d_in[7];
    const float* gW0   = (const float*)d_in[8];
    const float* gb0   = (const float*)d_in[9];
    const float* gW1   = (const float*)d_in[10];
    const float* gb1   = (const float*)d_in[11];
    const float* gW2   = (const float*)d_in[12];
    const float* gb2   = (const float*)d_in[13];
    const float* gateW = (const float*)d_in[14];
    const float* gateb = (const float*)d_in[15];
    const float* pW1   = (const float*)d_in[16];
    const float* pb1   = (const float*)d_in[17];
    const float* pW2   = (const float*)d_in[18];
    const float* pb2   = (const float*)d_in[19];
    const float* cW    = (const float*)d_in[20];
    const float* cb    = (const float*)d_in[21];

    const int N = in_sizes[0] / 128;
    const int E = in_sizes[1] / 2;
    const int* e_src = edge;          // edge_index[0]
    const int* e_dst = edge + E;      // edge_index[1]

    float* fws   = (float*)d_ws;
    int*   deg   = (int*)d_ws;                 // N ints
    float* dinv  = fws + (size_t)N;            // N
    float* h_mlp = fws + 2 * (size_t)N;        // 64N
    float* bufA  = fws + 66 * (size_t)N;       // 64N  (hw_scaled)
    float* bufB  = fws + 130 * (size_t)N;      // 64N  (agg)
    float* bufC  = fws + 194 * (size_t)N;      // 64N  (hg)

    float* logits = (float*)d_out;
    float* zproj  = (float*)d_out + N;

    const int nblk_rows = (N + 3) / 4;        // 25000
    const int nblk_edge = (E + 3) / 4;        // 300000
    const int nblk_n64  = (N * 64 + 255) / 256;

    hipMemsetAsync(deg, 0, (size_t)N * sizeof(int), stream);
    deg_kernel<<<(E + 255) / 256, 256, 0, stream>>>(e_dst, E, deg);
    dinv_kernel<<<(N + 255) / 256, 256, 0, stream>>>(deg, dinv, N);

    // layer 0 (K=128) + MLP branch fused
    gemm128_fused<<<nblk_rows, 256, 0, stream>>>(x, W1, b1, gamma, beta, rmean, rvar,
                                                 gW0, dinv, h_mlp, bufA, bufB, N);
    scatter_kernel<<<nblk_edge, 256, 0, stream>>>(e_src, e_dst, bufA, dinv, bufB, E);
    finalize_kernel<<<nblk_n64, 256, 0, stream>>>(bufB, gb0, bufC, N * 64);

    // layer 1
    gemm64_layer<<<nblk_rows, 256, 0, stream>>>(bufC, gW1, dinv, bufA, bufB, N);
    scatter_kernel<<<nblk_edge, 256, 0, stream>>>(e_src, e_dst, bufA, dinv, bufB, E);
    finalize_kernel<<<nblk_n64, 256, 0, stream>>>(bufB, gb1, bufC, N * 64);

    // layer 2
    gemm64_layer<<<nblk_rows, 256, 0, stream>>>(bufC, gW2, dinv, bufA, bufB, N);
    scatter_kernel<<<nblk_edge, 256, 0, stream>>>(e_src, e_dst, bufA, dinv, bufB, E);
    finalize_kernel<<<nblk_n64, 256, 0, stream>>>(bufB, gb2, bufC, N * 64);

    // head
    head_kernel<<<nblk_rows, 256, 0, stream>>>(h_mlp, bufC, gateW, gateb,
                                               pW1, pb1, pW2, pb2, cW, cb,
                                               logits, zproj, N);
}

// Round 2
// 847.721 us; speedup vs baseline: 1.5740x; 1.5740x over previous
//
#include <hip/hip_runtime.h>
#include <hip/hip_bf16.h>

// BiomarkerGNN: N=100000, E=1200000, F=128, HID=64, PROJ=32.
// Round 2: replace f32-atomic scatter with CSR + wave-per-dst-node gather.
// Fusions: finalize(bias+relu) + next-layer gemm64 + head all live in the
// aggregate kernel's epilogue.
//
// Pipeline:
//   memset deg; deg histogram (int atomics); scanA/B/C (exclusive prefix sum,
//   also writes dinv + cursor); fill_csr (atomic cursor allocation);
//   gemm128_fused: h_mlp = relu(BN(x@W1+b1)); hwA = (x@gW0)*dinv[row]
//   agg<GEMM>(hwA -> hwB): hg0=relu(dinv*(self+Σsrc)+gb0); hwB=(hg0@gW1)*dinv
//   agg<GEMM>(hwB -> hwA): hg1=relu(...+gb1);              hwA=(hg1@gW2)*dinv
//   agg<HEAD>(hwA):        hg2=relu(...+gb2); gate/fuse/proj/cls -> out

#define HID 64

__global__ __launch_bounds__(256) void deg_kernel(const int* __restrict__ dst, int E,
                                                  int* __restrict__ deg) {
    int e = blockIdx.x * 256 + threadIdx.x;
    if (e < E) atomicAdd(&deg[dst[e]], 1);
}

// Exclusive scan, 256 elems per block.
__global__ __launch_bounds__(256) void scanA(const int* __restrict__ deg,
                                             int* __restrict__ excl,
                                             int* __restrict__ partials, int N) {
    __shared__ int s[256];
    int t = threadIdx.x;
    int i = blockIdx.x * 256 + t;
    int v = (i < N) ? deg[i] : 0;
    s[t] = v;
    __syncthreads();
    for (int off = 1; off < 256; off <<= 1) {
        int u = (t >= off) ? s[t - off] : 0;
        __syncthreads();
        s[t] += u;
        __syncthreads();
    }
    if (i < N) excl[i] = s[t] - v;
    if (t == 255) partials[blockIdx.x] = s[255];
}

__global__ __launch_bounds__(512) void scanB(int* __restrict__ partials, int P) {
    __shared__ int s[512];
    int t = threadIdx.x;
    int v = (t < P) ? partials[t] : 0;
    s[t] = v;
    __syncthreads();
    for (int off = 1; off < 512; off <<= 1) {
        int u = (t >= off) ? s[t - off] : 0;
        __syncthreads();
        s[t] += u;
        __syncthreads();
    }
    if (t < P) partials[t] = s[t] - v;  // exclusive
}

__global__ __launch_bounds__(256) void scanC(const int* __restrict__ excl,
                                             const int* __restrict__ partials,
                                             const int* __restrict__ deg,
                                             int* __restrict__ row_start,
                                             int* __restrict__ cursor,
                                             float* __restrict__ dinv, int N, int E) {
    int i = blockIdx.x * 256 + threadIdx.x;
    if (i < N) {
        int rs = excl[i] + partials[blockIdx.x];
        row_start[i] = rs;
        cursor[i] = rs;
        dinv[i] = rsqrtf((float)deg[i] + 1.0f);  // +1 = self loop
        if (i == 0) row_start[N] = E;
    }
}

__global__ __launch_bounds__(256) void fill_csr(const int* __restrict__ src,
                                                const int* __restrict__ dst, int E,
                                                int* __restrict__ cursor,
                                                int* __restrict__ csr_src) {
    int e = blockIdx.x * 256 + threadIdx.x;
    if (e < E) {
        int pos = atomicAdd(&cursor[dst[e]], 1);
        csr_src[pos] = src[e];
    }
}

// 4 rows/block, 64 cols. MLP branch (W1+BN+relu) and GCN layer-0 matmul.
__global__ __launch_bounds__(256) void gemm128_fused(
    const float* __restrict__ x,
    const float* __restrict__ W1, const float* __restrict__ b1,
    const float* __restrict__ gamma, const float* __restrict__ beta,
    const float* __restrict__ rmean, const float* __restrict__ rvar,
    const float* __restrict__ gW0,
    const float* __restrict__ dinv,
    float* __restrict__ h_mlp, float* __restrict__ hw_s, int N) {
    __shared__ float sx[4][128];
    int tid = threadIdx.x;
    int rblk = blockIdx.x * 4;
    for (int i = tid; i < 512; i += 256) {
        int r = i >> 7, k = i & 127;
        int row = rblk + r;
        sx[r][k] = (row < N) ? x[(size_t)row * 128 + k] : 0.0f;
    }
    __syncthreads();
    int r = tid >> 6, c = tid & 63;
    int row = rblk + r;
    if (row >= N) return;
    float acc1 = 0.f, acc2 = 0.f;
#pragma unroll 8
    for (int k = 0; k < 128; ++k) {
        float xv = sx[r][k];
        acc1 = fmaf(xv, W1[k * HID + c], acc1);
        acc2 = fmaf(xv, gW0[k * HID + c], acc2);
    }
    float h = (acc1 + b1[c] - rmean[c]) * rsqrtf(rvar[c] + 1e-5f) * gamma[c] + beta[c];
    h_mlp[(size_t)row * HID + c] = fmaxf(h, 0.f);
    hw_s[(size_t)row * HID + c] = acc2 * dinv[row];
}

// Wave-per-dst-node aggregation with fused epilogue.
// MODE 0: hg = relu(dinv*(self+sum) + gb); out = (hg @ Wn) * dinv  [next hw_s]
// MODE 1: head — gate/fuse/projection/classifier.
template <int MODE>
__global__ __launch_bounds__(256) void agg_kernel(
    const float* __restrict__ hw_s, const int* __restrict__ row_start,
    const int* __restrict__ csr_src, const float* __restrict__ dinv,
    const float* __restrict__ gb,
    const float* __restrict__ Wn,                                    // MODE 0
    const float* __restrict__ h_mlp,                                 // MODE 1 ...
    const float* __restrict__ gateW, const float* __restrict__ gateb,
    const float* __restrict__ pW1, const float* __restrict__ pb1,
    const float* __restrict__ pW2, const float* __restrict__ pb2,
    const float* __restrict__ cW, const float* __restrict__ cb,
    float* __restrict__ out,                                         // hw_next | logits
    float* __restrict__ zproj, int N) {
    __shared__ float sW[64 * 64];
    __shared__ float sW2[64 * 64];
    int tid = threadIdx.x, lane = tid & 63, wid = tid >> 6;
    if (MODE == 0) {
        for (int i = tid; i < 4096; i += 256) sW[i] = Wn[i];
    } else {
        for (int i = tid; i < 4096; i += 256) sW[i] = pW1[i];
        for (int i = tid; i < 4096; i += 256) {
            int k = i >> 6, c = i & 63;
            sW2[i] = (c < 32) ? pW2[k * 32 + c] : 0.f;
        }
    }
    __syncthreads();

    // per-lane invariants (MODE 1)
    float gWa = 0.f, gWb = 0.f, pb1v = 0.f, pb2v = 0.f, cWv = 0.f, gb0v = 0.f, cb0v = 0.f;
    if (MODE == 1) {
        gWa = gateW[lane];
        gWb = gateW[64 + lane];
        pb1v = pb1[lane];
        pb2v = (lane < 32) ? pb2[lane] : 0.f;
        cWv = cW[lane];
        gb0v = gateb[0];
        cb0v = cb[0];
    }
    float gbv = gb[lane];

    int gw = blockIdx.x * 4 + wid;
    int nw = gridDim.x * 4;
    for (int d = gw; d < N; d += nw) {
        int rs = row_start[d], re = row_start[d + 1];
        float acc = hw_s[(size_t)d * HID + lane];  // self loop (already *dinv[d])
        for (int base = rs; base < re; base += 64) {
            int idx = (base + lane < re) ? csr_src[base + lane] : 0;
            int n = re - base;
            if (n > 64) n = 64;
            for (int j = 0; j < n; ++j) {
                int s = __shfl(idx, j, 64);
                acc += hw_s[(size_t)s * HID + lane];
            }
        }
        float dv = dinv[d];
        float hg = fmaxf(fmaf(acc, dv, gbv), 0.f);

        if (MODE == 0) {
            float o = 0.f;
#pragma unroll 8
            for (int k = 0; k < 64; ++k) {
                float hgk = __shfl(hg, k, 64);
                o = fmaf(hgk, sW[k * HID + lane], o);
            }
            out[(size_t)d * HID + lane] = o * dv;
        } else {
            float hm = h_mlp[(size_t)d * HID + lane];
            float p = fmaf(hm, gWa, hg * gWb);
#pragma unroll
            for (int m = 32; m >= 1; m >>= 1) p += __shfl_xor(p, m, 64);
            float gate = 1.f / (1.f + expf(-(p + gb0v)));
            float hf = gate * hg + (1.f - gate) * hm;
            float t = pb1v;
#pragma unroll 8
            for (int k = 0; k < 64; ++k) {
                float hfk = __shfl(hf, k, 64);
                t = fmaf(hfk, sW[k * HID + lane], t);
            }
            t = fmaxf(t, 0.f);
            float z = pb2v;
#pragma unroll 8
            for (int k = 0; k < 64; ++k) {
                float tk = __shfl(t, k, 64);
                z = fmaf(tk, sW2[k * HID + lane], z);
            }
            if (lane < 32) zproj[(size_t)d * 32 + lane] = z;
            float q = hf * cWv;
#pragma unroll
            for (int m = 32; m >= 1; m >>= 1) q += __shfl_xor(q, m, 64);
            if (lane == 0) out[d] = q + cb0v;
        }
    }
}

extern "C" void kernel_launch(void* const* d_in, const int* in_sizes, int n_in,
                              void* d_out, int out_size, void* d_ws, size_t ws_size,
                              hipStream_t stream) {
    const float* x     = (const float*)d_in[0];
    const int*   edge  = (const int*)d_in[1];
    const float* W1    = (const float*)d_in[2];
    const float* b1    = (const float*)d_in[3];
    const float* gamma = (const float*)d_in[4];
    const float* beta  = (const float*)d_in[5];
    const float* rmean = (const float*)d_in[6];
    const float* rvar  = (const float*)d_in[7];
    const float* gW0   = (const float*)d_in[8];
    const float* gb0   = (const float*)d_in[9];
    const float* gW1   = (const float*)d_in[10];
    const float* gb1   = (const float*)d_in[11];
    const float* gW2   = (const float*)d_in[12];
    const float* gb2   = (const float*)d_in[13];
    const float* gateW = (const float*)d_in[14];
    const float* gateb = (const float*)d_in[15];
    const float* pW1   = (const float*)d_in[16];
    const float* pb1   = (const float*)d_in[17];
    const float* pW2   = (const float*)d_in[18];
    const float* pb2   = (const float*)d_in[19];
    const float* cW    = (const float*)d_in[20];
    const float* cb    = (const float*)d_in[21];

    const int N = in_sizes[0] / 128;
    const int E = in_sizes[1] / 2;
    const int* e_src = edge;
    const int* e_dst = edge + E;

    // workspace layout (4B units)
    char* ws = (char*)d_ws;
    size_t o = 0;
    int* deg       = (int*)(ws + o); o += (size_t)N * 4;
    int* excl      = (int*)(ws + o); o += (size_t)N * 4;
    int* partials  = (int*)(ws + o); o += 512 * 4;
    int* row_start = (int*)(ws + o); o += ((size_t)N + 1) * 4;
    int* cursor    = (int*)(ws + o); o += (size_t)N * 4;
    int* csr_src   = (int*)(ws + o); o += (size_t)E * 4;
    float* dinv    = (float*)(ws + o); o += (size_t)N * 4;
    float* h_mlp   = (float*)(ws + o); o += (size_t)N * 64 * 4;
    float* hwA     = (float*)(ws + o); o += (size_t)N * 64 * 4;
    float* hwB     = (float*)(ws + o); o += (size_t)N * 64 * 4;

    float* logits = (float*)d_out;
    float* zproj  = (float*)d_out + N;

    const int nblkN  = (N + 255) / 256;      // 391
    const int nblkE  = (E + 255) / 256;
    const int nblkR  = (N + 3) / 4;          // gemm128 row blocks
    const int aggBlk = 4096;

    hipMemsetAsync(deg, 0, (size_t)N * sizeof(int), stream);
    deg_kernel<<<nblkE, 256, 0, stream>>>(e_dst, E, deg);
    scanA<<<nblkN, 256, 0, stream>>>(deg, excl, partials, N);
    scanB<<<1, 512, 0, stream>>>(partials, nblkN);
    scanC<<<nblkN, 256, 0, stream>>>(excl, partials, deg, row_start, cursor, dinv, N, E);
    fill_csr<<<nblkE, 256, 0, stream>>>(e_src, e_dst, E, cursor, csr_src);

    gemm128_fused<<<nblkR, 256, 0, stream>>>(x, W1, b1, gamma, beta, rmean, rvar,
                                             gW0, dinv, h_mlp, hwA, N);

    // layer 0 -> produce hwB for layer 1
    agg_kernel<0><<<aggBlk, 256, 0, stream>>>(hwA, row_start, csr_src, dinv, gb0,
                                              gW1, nullptr, nullptr, nullptr,
                                              nullptr, nullptr, nullptr, nullptr,
                                              nullptr, nullptr, hwB, nullptr, N);
    // layer 1 -> produce hwA for layer 2
    agg_kernel<0><<<aggBlk, 256, 0, stream>>>(hwB, row_start, csr_src, dinv, gb1,
                                              gW2, nullptr, nullptr, nullptr,
                                              nullptr, nullptr, nullptr, nullptr,
                                              nullptr, nullptr, hwA, nullptr, N);
    // layer 2 + head
    agg_kernel<1><<<aggBlk, 256, 0, stream>>>(hwA, row_start, csr_src, dinv, gb2,
                                              nullptr, h_mlp, gateW, gateb,
                                              pW1, pb1, pW2, pb2, cW, cb,
                                              logits, zproj, N);
}

// Round 3
// 781.228 us; speedup vs baseline: 1.7080x; 1.0851x over previous
//
#include <hip/hip_runtime.h>
#include <hip/hip_bf16.h>

// BiomarkerGNN: N=100000, E=1200000, F=128, HID=64, PROJ=32.
// Round 3: bf16 gather buffers (halve random-gather traffic), MODE-sized LDS
// (occupancy 40%->~100% for MODE 0), 4-wide unrolled gather (4 outstanding
// loads per wave instead of a serial dependent chain).
//
// Pipeline:
//   deg histogram -> scan -> CSR fill (by dst)
//   gemm128_fused: h_mlp(f32) = relu(BN(x@W1+b1)); hwA(bf16) = (x@gW0)*dinv
//   agg<0>(hwA->hwB): hg=relu(dinv*(self+sum)+gb0); hwB=(hg@gW1)*dinv
//   agg<0>(hwB->hwA): ... gb1, gW2
//   agg<1>(hwA): hg2 + gate/fuse/projection/classifier -> logits, zproj

#define HID 64

typedef unsigned short ushort_t;

__device__ __forceinline__ float bf2f(ushort_t u) {
    unsigned v = ((unsigned)u) << 16;
    union { unsigned u; float f; } c;
    c.u = v;
    return c.f;
}
__device__ __forceinline__ ushort_t f2bf(float f) {
    union { float f; unsigned u; } c;
    c.f = f;
    unsigned u = c.u;
    unsigned r = (u + 0x7FFFu + ((u >> 16) & 1u)) >> 16;  // RNE
    return (ushort_t)r;
}

__global__ __launch_bounds__(256) void deg_kernel(const int* __restrict__ dst, int E,
                                                  int* __restrict__ deg) {
    int e = blockIdx.x * 256 + threadIdx.x;
    if (e < E) atomicAdd(&deg[dst[e]], 1);
}

__global__ __launch_bounds__(256) void scanA(const int* __restrict__ deg,
                                             int* __restrict__ excl,
                                             int* __restrict__ partials, int N) {
    __shared__ int s[256];
    int t = threadIdx.x;
    int i = blockIdx.x * 256 + t;
    int v = (i < N) ? deg[i] : 0;
    s[t] = v;
    __syncthreads();
    for (int off = 1; off < 256; off <<= 1) {
        int u = (t >= off) ? s[t - off] : 0;
        __syncthreads();
        s[t] += u;
        __syncthreads();
    }
    if (i < N) excl[i] = s[t] - v;
    if (t == 255) partials[blockIdx.x] = s[255];
}

__global__ __launch_bounds__(512) void scanB(int* __restrict__ partials, int P) {
    __shared__ int s[512];
    int t = threadIdx.x;
    int v = (t < P) ? partials[t] : 0;
    s[t] = v;
    __syncthreads();
    for (int off = 1; off < 512; off <<= 1) {
        int u = (t >= off) ? s[t - off] : 0;
        __syncthreads();
        s[t] += u;
        __syncthreads();
    }
    if (t < P) partials[t] = s[t] - v;
}

__global__ __launch_bounds__(256) void scanC(const int* __restrict__ excl,
                                             const int* __restrict__ partials,
                                             const int* __restrict__ deg,
                                             int* __restrict__ row_start,
                                             int* __restrict__ cursor,
                                             float* __restrict__ dinv, int N, int E) {
    int i = blockIdx.x * 256 + threadIdx.x;
    if (i < N) {
        int rs = excl[i] + partials[blockIdx.x];
        row_start[i] = rs;
        cursor[i] = rs;
        dinv[i] = rsqrtf((float)deg[i] + 1.0f);
        if (i == 0) row_start[N] = E;
    }
}

__global__ __launch_bounds__(256) void fill_csr(const int* __restrict__ src,
                                                const int* __restrict__ dst, int E,
                                                int* __restrict__ cursor,
                                                int* __restrict__ csr_src) {
    int e = blockIdx.x * 256 + threadIdx.x;
    if (e < E) {
        int pos = atomicAdd(&cursor[dst[e]], 1);
        csr_src[pos] = src[e];
    }
}

__global__ __launch_bounds__(256) void gemm128_fused(
    const float* __restrict__ x,
    const float* __restrict__ W1, const float* __restrict__ b1,
    const float* __restrict__ gamma, const float* __restrict__ beta,
    const float* __restrict__ rmean, const float* __restrict__ rvar,
    const float* __restrict__ gW0,
    const float* __restrict__ dinv,
    float* __restrict__ h_mlp, ushort_t* __restrict__ hw_s, int N) {
    __shared__ float sx[4][128];
    int tid = threadIdx.x;
    int rblk = blockIdx.x * 4;
    for (int i = tid; i < 512; i += 256) {
        int r = i >> 7, k = i & 127;
        int row = rblk + r;
        sx[r][k] = (row < N) ? x[(size_t)row * 128 + k] : 0.0f;
    }
    __syncthreads();
    int r = tid >> 6, c = tid & 63;
    int row = rblk + r;
    if (row >= N) return;
    float acc1 = 0.f, acc2 = 0.f;
#pragma unroll 8
    for (int k = 0; k < 128; ++k) {
        float xv = sx[r][k];
        acc1 = fmaf(xv, W1[k * HID + c], acc1);
        acc2 = fmaf(xv, gW0[k * HID + c], acc2);
    }
    float h = (acc1 + b1[c] - rmean[c]) * rsqrtf(rvar[c] + 1e-5f) * gamma[c] + beta[c];
    h_mlp[(size_t)row * HID + c] = fmaxf(h, 0.f);
    hw_s[(size_t)row * HID + c] = f2bf(acc2 * dinv[row]);
}

// Wave-per-dst-node aggregation with fused epilogue. hw_s is bf16.
// MODE 0: hg = relu(dinv*(self+sum) + gb); out_bf = (hg @ Wn) * dinv
// MODE 1: head — gate/fuse/projection/classifier -> logits, zproj (f32)
template <int MODE>
__global__ __launch_bounds__(256) void agg_kernel(
    const ushort_t* __restrict__ hw_s, const int* __restrict__ row_start,
    const int* __restrict__ csr_src, const float* __restrict__ dinv,
    const float* __restrict__ gb,
    const float* __restrict__ Wn,
    const float* __restrict__ h_mlp,
    const float* __restrict__ gateW, const float* __restrict__ gateb,
    const float* __restrict__ pW1, const float* __restrict__ pb1,
    const float* __restrict__ pW2, const float* __restrict__ pb2,
    const float* __restrict__ cW, const float* __restrict__ cb,
    ushort_t* __restrict__ out_bf,
    float* __restrict__ logits, float* __restrict__ zproj, int N) {
    __shared__ float sW[64 * 64];
    __shared__ float sW2[MODE == 1 ? 64 * 32 : 1];  // 16KB MODE0, 24KB MODE1
    int tid = threadIdx.x, lane = tid & 63, wid = tid >> 6;
    if (MODE == 0) {
        for (int i = tid; i < 4096; i += 256) sW[i] = Wn[i];
    } else {
        for (int i = tid; i < 4096; i += 256) sW[i] = pW1[i];
        for (int i = tid; i < 2048; i += 256) sW2[i] = pW2[i];
    }
    __syncthreads();

    float gWa = 0.f, gWb = 0.f, pb1v = 0.f, pb2v = 0.f, cWv = 0.f, gb0v = 0.f, cb0v = 0.f;
    if (MODE == 1) {
        gWa = gateW[lane];
        gWb = gateW[64 + lane];
        pb1v = pb1[lane];
        pb2v = (lane < 32) ? pb2[lane] : 0.f;
        cWv = cW[lane];
        gb0v = gateb[0];
        cb0v = cb[0];
    }
    float gbv = gb[lane];

    int gw = blockIdx.x * 4 + wid;
    int nw = gridDim.x * 4;
    for (int d = gw; d < N; d += nw) {
        int rs = row_start[d], re = row_start[d + 1];
        float a0 = bf2f(hw_s[(size_t)d * HID + lane]);  // self loop
        float a1 = 0.f, a2 = 0.f, a3 = 0.f;
        for (int base = rs; base < re; base += 64) {
            int idx = (base + lane < re) ? csr_src[base + lane] : 0;
            int m = re - base;
            if (m > 64) m = 64;
            int j = 0;
            for (; j + 4 <= m; j += 4) {
                int s0 = __shfl(idx, j, 64);
                int s1 = __shfl(idx, j + 1, 64);
                int s2 = __shfl(idx, j + 2, 64);
                int s3 = __shfl(idx, j + 3, 64);
                a0 += bf2f(hw_s[(size_t)s0 * HID + lane]);
                a1 += bf2f(hw_s[(size_t)s1 * HID + lane]);
                a2 += bf2f(hw_s[(size_t)s2 * HID + lane]);
                a3 += bf2f(hw_s[(size_t)s3 * HID + lane]);
            }
            for (; j < m; ++j) {
                int s0 = __shfl(idx, j, 64);
                a1 += bf2f(hw_s[(size_t)s0 * HID + lane]);
            }
        }
        float acc = (a0 + a1) + (a2 + a3);
        float dv = dinv[d];
        float hg = fmaxf(fmaf(acc, dv, gbv), 0.f);

        if (MODE == 0) {
            float o = 0.f;
#pragma unroll 8
            for (int k = 0; k < 64; ++k) {
                float hgk = __shfl(hg, k, 64);
                o = fmaf(hgk, sW[k * HID + lane], o);
            }
            out_bf[(size_t)d * HID + lane] = f2bf(o * dv);
        } else {
            float hm = h_mlp[(size_t)d * HID + lane];
            float p = fmaf(hm, gWa, hg * gWb);
#pragma unroll
            for (int m2 = 32; m2 >= 1; m2 >>= 1) p += __shfl_xor(p, m2, 64);
            float gate = 1.f / (1.f + expf(-(p + gb0v)));
            float hf = gate * hg + (1.f - gate) * hm;
            float t = pb1v;
#pragma unroll 8
            for (int k = 0; k < 64; ++k) {
                float hfk = __shfl(hf, k, 64);
                t = fmaf(hfk, sW[k * HID + lane], t);
            }
            t = fmaxf(t, 0.f);
            float z = pb2v;
#pragma unroll 8
            for (int k = 0; k < 64; ++k) {
                float tk = __shfl(t, k, 64);
                if (lane < 32) z = fmaf(tk, sW2[k * 32 + lane], z);
            }
            if (lane < 32) zproj[(size_t)d * 32 + lane] = z;
            float q = hf * cWv;
#pragma unroll
            for (int m2 = 32; m2 >= 1; m2 >>= 1) q += __shfl_xor(q, m2, 64);
            if (lane == 0) logits[d] = q + cb0v;
        }
    }
}

extern "C" void kernel_launch(void* const* d_in, const int* in_sizes, int n_in,
                              void* d_out, int out_size, void* d_ws, size_t ws_size,
                              hipStream_t stream) {
    const float* x     = (const float*)d_in[0];
    const int*   edge  = (const int*)d_in[1];
    const float* W1    = (const float*)d_in[2];
    const float* b1    = (const float*)d_in[3];
    const float* gamma = (const float*)d_in[4];
    const float* beta  = (const float*)d_in[5];
    const float* rmean = (const float*)d_in[6];
    const float* rvar  = (const float*)d_in[7];
    const float* gW0   = (const float*)d_in[8];
    const float* gb0   = (const float*)d_in[9];
    const float* gW1   = (const float*)d_in[10];
    const float* gb1   = (const float*)d_in[11];
    const float* gW2   = (const float*)d_in[12];
    const float* gb2   = (const float*)d_in[13];
    const float* gateW = (const float*)d_in[14];
    const float* gateb = (const float*)d_in[15];
    const float* pW1   = (const float*)d_in[16];
    const float* pb1   = (const float*)d_in[17];
    const float* pW2   = (const float*)d_in[18];
    const float* pb2   = (const float*)d_in[19];
    const float* cW    = (const float*)d_in[20];
    const float* cb    = (const float*)d_in[21];

    const int N = in_sizes[0] / 128;
    const int E = in_sizes[1] / 2;
    const int* e_src = edge;
    const int* e_dst = edge + E;

    char* ws = (char*)d_ws;
    size_t o = 0;
    int* deg       = (int*)(ws + o); o += (size_t)N * 4;
    int* excl      = (int*)(ws + o); o += (size_t)N * 4;
    int* partials  = (int*)(ws + o); o += 512 * 4;
    int* row_start = (int*)(ws + o); o += ((size_t)N + 1) * 4;
    int* cursor    = (int*)(ws + o); o += (size_t)N * 4;
    int* csr_src   = (int*)(ws + o); o += (size_t)E * 4;
    float* dinv    = (float*)(ws + o); o += (size_t)N * 4;
    float* h_mlp   = (float*)(ws + o); o += (size_t)N * 64 * 4;
    ushort_t* hwA  = (ushort_t*)(ws + o); o += (size_t)N * 64 * 2;
    ushort_t* hwB  = (ushort_t*)(ws + o); o += (size_t)N * 64 * 2;

    float* logits = (float*)d_out;
    float* zproj  = (float*)d_out + N;

    const int nblkN  = (N + 255) / 256;
    const int nblkE  = (E + 255) / 256;
    const int nblkR  = (N + 3) / 4;
    const int aggBlk = 4096;

    hipMemsetAsync(deg, 0, (size_t)N * sizeof(int), stream);
    deg_kernel<<<nblkE, 256, 0, stream>>>(e_dst, E, deg);
    scanA<<<nblkN, 256, 0, stream>>>(deg, excl, partials, N);
    scanB<<<1, 512, 0, stream>>>(partials, nblkN);
    scanC<<<nblkN, 256, 0, stream>>>(excl, partials, deg, row_start, cursor, dinv, N, E);
    fill_csr<<<nblkE, 256, 0, stream>>>(e_src, e_dst, E, cursor, csr_src);

    gemm128_fused<<<nblkR, 256, 0, stream>>>(x, W1, b1, gamma, beta, rmean, rvar,
                                             gW0, dinv, h_mlp, hwA, N);

    agg_kernel<0><<<aggBlk, 256, 0, stream>>>(hwA, row_start, csr_src, dinv, gb0,
                                              gW1, nullptr, nullptr, nullptr,
                                              nullptr, nullptr, nullptr, nullptr,
                                              nullptr, nullptr, hwB, nullptr, nullptr, N);
    agg_kernel<0><<<aggBlk, 256, 0, stream>>>(hwB, row_start, csr_src, dinv, gb1,
                                              gW2, nullptr, nullptr, nullptr,
                                              nullptr, nullptr, nullptr, nullptr,
                                              nullptr, nullptr, hwA, nullptr, nullptr, N);
    agg_kernel<1><<<aggBlk, 256, 0, stream>>>(hwA, row_start, csr_src, dinv, gb2,
                                              nullptr, h_mlp, gateW, gateb,
                                              pW1, pb1, pW2, pb2, cW, cb,
                                              nullptr, logits, zproj, N);
}

// Round 4
// 780.935 us; speedup vs baseline: 1.7086x; 1.0004x over previous
//
#include <hip/hip_runtime.h>
#include <hip/hip_bf16.h>

// BiomarkerGNN: N=100000, E=1200000, F=128, HID=64, PROJ=32.
// Round 4: wide gathers (16 lanes x 8B per row => 4 edges per VMEM instr,
// 16-edge superrounds => whole node in flight), dynamic LDS sized per mode
// (16KB MODE0 -> 8 blocks/CU), 16B-aligned workspace.
//
// Pipeline:
//   deg histogram -> scan -> CSR fill (by dst)
//   gemm128_fused: h_mlp(f32) = relu(BN(x@W1+b1)); hwA(bf16) = (x@gW0)*dinv
//   agg<0>(hwA->hwB): hg=relu(dinv*(self+sum)+gb0); hwB=(hg@gW1)*dinv
//   agg<0>(hwB->hwA): ... gb1, gW2
//   agg<1>(hwA): hg2 + gate/fuse/projection/classifier -> logits, zproj

#define HID 64

typedef unsigned short ushort_t;
typedef unsigned int uint_t;

__device__ __forceinline__ float bf2f(ushort_t u) {
    union { unsigned u; float f; } c;
    c.u = ((unsigned)u) << 16;
    return c.f;
}
__device__ __forceinline__ float bflo(uint_t u) {
    union { unsigned u; float f; } c;
    c.u = u << 16;
    return c.f;
}
__device__ __forceinline__ float bfhi(uint_t u) {
    union { unsigned u; float f; } c;
    c.u = u & 0xFFFF0000u;
    return c.f;
}
__device__ __forceinline__ ushort_t f2bf(float f) {
    union { float f; unsigned u; } c;
    c.f = f;
    unsigned u = c.u;
    unsigned r = (u + 0x7FFFu + ((u >> 16) & 1u)) >> 16;  // RNE
    return (ushort_t)r;
}

__global__ __launch_bounds__(256) void deg_kernel(const int* __restrict__ dst, int E,
                                                  int* __restrict__ deg) {
    int e = blockIdx.x * 256 + threadIdx.x;
    if (e < E) atomicAdd(&deg[dst[e]], 1);
}

__global__ __launch_bounds__(256) void scanA(const int* __restrict__ deg,
                                             int* __restrict__ excl,
                                             int* __restrict__ partials, int N) {
    __shared__ int s[256];
    int t = threadIdx.x;
    int i = blockIdx.x * 256 + t;
    int v = (i < N) ? deg[i] : 0;
    s[t] = v;
    __syncthreads();
    for (int off = 1; off < 256; off <<= 1) {
        int u = (t >= off) ? s[t - off] : 0;
        __syncthreads();
        s[t] += u;
        __syncthreads();
    }
    if (i < N) excl[i] = s[t] - v;
    if (t == 255) partials[blockIdx.x] = s[255];
}

__global__ __launch_bounds__(512) void scanB(int* __restrict__ partials, int P) {
    __shared__ int s[512];
    int t = threadIdx.x;
    int v = (t < P) ? partials[t] : 0;
    s[t] = v;
    __syncthreads();
    for (int off = 1; off < 512; off <<= 1) {
        int u = (t >= off) ? s[t - off] : 0;
        __syncthreads();
        s[t] += u;
        __syncthreads();
    }
    if (t < P) partials[t] = s[t] - v;
}

__global__ __launch_bounds__(256) void scanC(const int* __restrict__ excl,
                                             const int* __restrict__ partials,
                                             const int* __restrict__ deg,
                                             int* __restrict__ row_start,
                                             int* __restrict__ cursor,
                                             float* __restrict__ dinv, int N, int E) {
    int i = blockIdx.x * 256 + threadIdx.x;
    if (i < N) {
        int rs = excl[i] + partials[blockIdx.x];
        row_start[i] = rs;
        cursor[i] = rs;
        dinv[i] = rsqrtf((float)deg[i] + 1.0f);
        if (i == 0) row_start[N] = E;
    }
}

__global__ __launch_bounds__(256) void fill_csr(const int* __restrict__ src,
                                                const int* __restrict__ dst, int E,
                                                int* __restrict__ cursor,
                                                int* __restrict__ csr_src) {
    int e = blockIdx.x * 256 + threadIdx.x;
    if (e < E) {
        int pos = atomicAdd(&cursor[dst[e]], 1);
        csr_src[pos] = src[e];
    }
}

__global__ __launch_bounds__(256) void gemm128_fused(
    const float* __restrict__ x,
    const float* __restrict__ W1, const float* __restrict__ b1,
    const float* __restrict__ gamma, const float* __restrict__ beta,
    const float* __restrict__ rmean, const float* __restrict__ rvar,
    const float* __restrict__ gW0,
    const float* __restrict__ dinv,
    float* __restrict__ h_mlp, ushort_t* __restrict__ hw_s, int N) {
    __shared__ float sx[4][128];
    int tid = threadIdx.x;
    int rblk = blockIdx.x * 4;
    for (int i = tid; i < 512; i += 256) {
        int r = i >> 7, k = i & 127;
        int row = rblk + r;
        sx[r][k] = (row < N) ? x[(size_t)row * 128 + k] : 0.0f;
    }
    __syncthreads();
    int r = tid >> 6, c = tid & 63;
    int row = rblk + r;
    if (row >= N) return;
    float acc1 = 0.f, acc2 = 0.f;
#pragma unroll 8
    for (int k = 0; k < 128; ++k) {
        float xv = sx[r][k];
        acc1 = fmaf(xv, W1[k * HID + c], acc1);
        acc2 = fmaf(xv, gW0[k * HID + c], acc2);
    }
    float h = (acc1 + b1[c] - rmean[c]) * rsqrtf(rvar[c] + 1e-5f) * gamma[c] + beta[c];
    h_mlp[(size_t)row * HID + c] = fmaxf(h, 0.f);
    hw_s[(size_t)row * HID + c] = f2bf(acc2 * dinv[row]);
}

// Wave-per-dst-node aggregation, wide-gather version.
// Gather: 16 lanes x uint2 (8B = 4 bf16) per source row => 4 edges per VMEM
// instruction; 16-edge superround issues 4 independent loads back-to-back.
// Lane L: slot = L>>4 (edge within quad), sub = L&15 (col quad 4*sub..4*sub+3).
// MODE 0: hg = relu(dinv*(self+sum)+gb); out_bf = (hg @ Wn)*dinv
// MODE 1: head -> logits, zproj.
template <int MODE>
__global__ __launch_bounds__(256) void agg_kernel(
    const ushort_t* __restrict__ hw_s, const int* __restrict__ row_start,
    const int* __restrict__ csr_src, const float* __restrict__ dinv,
    const float* __restrict__ gb,
    const float* __restrict__ Wn,
    const float* __restrict__ h_mlp,
    const float* __restrict__ gateW, const float* __restrict__ gateb,
    const float* __restrict__ pW1, const float* __restrict__ pb1,
    const float* __restrict__ pW2, const float* __restrict__ pb2,
    const float* __restrict__ cW, const float* __restrict__ cb,
    ushort_t* __restrict__ out_bf,
    float* __restrict__ logits, float* __restrict__ zproj, int N) {
    extern __shared__ float smem[];
    float* sW  = smem;          // 64*64
    float* sW2 = smem + 4096;   // 64*32 (MODE 1 only)
    int tid = threadIdx.x, lane = tid & 63, wid = tid >> 6;
    if (MODE == 0) {
        for (int i = tid; i < 4096; i += 256) sW[i] = Wn[i];
    } else {
        for (int i = tid; i < 4096; i += 256) sW[i] = pW1[i];
        for (int i = tid; i < 2048; i += 256) sW2[i] = pW2[i];
    }
    __syncthreads();

    float gWa = 0.f, gWb = 0.f, pb1v = 0.f, pb2v = 0.f, cWv = 0.f, gb0v = 0.f, cb0v = 0.f;
    if (MODE == 1) {
        gWa = gateW[lane];
        gWb = gateW[64 + lane];
        pb1v = pb1[lane];
        pb2v = (lane < 32) ? pb2[lane] : 0.f;
        cWv = cW[lane];
        gb0v = gateb[0];
        cb0v = cb[0];
    }
    float gbv = gb[lane];
    int slot = lane >> 4;      // 0..3: which edge of the quad
    int sub  = lane & 15;      // col quad index

    int gw = blockIdx.x * 4 + wid;
    int nw = gridDim.x * 4;
    for (int d = gw; d < N; d += nw) {
        int rs = row_start[d], re = row_start[d + 1];
        float selfv = bf2f(hw_s[(size_t)d * HID + lane]);  // lane=col layout
        float ax = 0.f, ay = 0.f, az = 0.f, aw = 0.f;      // slot-partial col quad
        for (int base = rs; base < re; base += 64) {
            int cnt = re - base;
            if (cnt > 64) cnt = 64;
            int idx = (base + lane < re) ? csr_src[base + lane] : 0;
            for (int j = 0; j < cnt; j += 16) {
                uint_t g0x, g0y, g1x, g1y, g2x, g2y, g3x, g3y;
                bool v0, v1, v2, v3;
                {
                    int e = j + slot;
                    v0 = (e < cnt);
                    int s = __shfl(idx, e, 64);
                    s = v0 ? s : 0;
                    const uint2* p = (const uint2*)(hw_s + (size_t)s * HID);
                    uint2 g = p[sub]; g0x = g.x; g0y = g.y;
                }
                {
                    int e = j + 4 + slot;
                    v1 = (e < cnt);
                    int s = __shfl(idx, e, 64);
                    s = v1 ? s : 0;
                    const uint2* p = (const uint2*)(hw_s + (size_t)s * HID);
                    uint2 g = p[sub]; g1x = g.x; g1y = g.y;
                }
                {
                    int e = j + 8 + slot;
                    v2 = (e < cnt);
                    int s = __shfl(idx, e, 64);
                    s = v2 ? s : 0;
                    const uint2* p = (const uint2*)(hw_s + (size_t)s * HID);
                    uint2 g = p[sub]; g2x = g.x; g2y = g.y;
                }
                {
                    int e = j + 12 + slot;
                    v3 = (e < cnt);
                    int s = __shfl(idx, e, 64);
                    s = v3 ? s : 0;
                    const uint2* p = (const uint2*)(hw_s + (size_t)s * HID);
                    uint2 g = p[sub]; g3x = g.x; g3y = g.y;
                }
                if (v0) { ax += bflo(g0x); ay += bfhi(g0x); az += bflo(g0y); aw += bfhi(g0y); }
                if (v1) { ax += bflo(g1x); ay += bfhi(g1x); az += bflo(g1y); aw += bfhi(g1y); }
                if (v2) { ax += bflo(g2x); ay += bfhi(g2x); az += bflo(g2y); aw += bfhi(g2y); }
                if (v3) { ax += bflo(g3x); ay += bfhi(g3x); az += bflo(g3y); aw += bfhi(g3y); }
            }
        }
        // reduce the 4 slot groups: after this every lane has quad totals
        ax += __shfl_xor(ax, 16, 64); ay += __shfl_xor(ay, 16, 64);
        az += __shfl_xor(az, 16, 64); aw += __shfl_xor(aw, 16, 64);
        ax += __shfl_xor(ax, 32, 64); ay += __shfl_xor(ay, 32, 64);
        az += __shfl_xor(az, 32, 64); aw += __shfl_xor(aw, 32, 64);
        // redistribute quad layout -> lane=col layout: col=lane comes from
        // source lane (lane>>2), component (lane&3)
        int srcl = lane >> 2;
        float t0 = __shfl(ax, srcl, 64);
        float t1 = __shfl(ay, srcl, 64);
        float t2 = __shfl(az, srcl, 64);
        float t3 = __shfl(aw, srcl, 64);
        int q = lane & 3;
        float sum = (q == 0) ? t0 : (q == 1) ? t1 : (q == 2) ? t2 : t3;
        sum += selfv;

        float dv = dinv[d];
        float hg = fmaxf(fmaf(sum, dv, gbv), 0.f);

        if (MODE == 0) {
            float o = 0.f;
#pragma unroll 8
            for (int k = 0; k < 64; ++k) {
                float hgk = __shfl(hg, k, 64);
                o = fmaf(hgk, sW[k * HID + lane], o);
            }
            out_bf[(size_t)d * HID + lane] = f2bf(o * dv);
        } else {
            float hm = h_mlp[(size_t)d * HID + lane];
            float p = fmaf(hm, gWa, hg * gWb);
#pragma unroll
            for (int m2 = 32; m2 >= 1; m2 >>= 1) p += __shfl_xor(p, m2, 64);
            float gate = 1.f / (1.f + expf(-(p + gb0v)));
            float hf = gate * hg + (1.f - gate) * hm;
            float t = pb1v;
#pragma unroll 8
            for (int k = 0; k < 64; ++k) {
                float hfk = __shfl(hf, k, 64);
                t = fmaf(hfk, sW[k * HID + lane], t);
            }
            t = fmaxf(t, 0.f);
            float z = pb2v;
#pragma unroll 8
            for (int k = 0; k < 64; ++k) {
                float tk = __shfl(t, k, 64);
                if (lane < 32) z = fmaf(tk, sW2[k * 32 + lane], z);
            }
            if (lane < 32) zproj[(size_t)d * 32 + lane] = z;
            float qq = hf * cWv;
#pragma unroll
            for (int m2 = 32; m2 >= 1; m2 >>= 1) qq += __shfl_xor(qq, m2, 64);
            if (lane == 0) logits[d] = qq + cb0v;
        }
    }
}

extern "C" void kernel_launch(void* const* d_in, const int* in_sizes, int n_in,
                              void* d_out, int out_size, void* d_ws, size_t ws_size,
                              hipStream_t stream) {
    const float* x     = (const float*)d_in[0];
    const int*   edge  = (const int*)d_in[1];
    const float* W1    = (const float*)d_in[2];
    const float* b1    = (const float*)d_in[3];
    const float* gamma = (const float*)d_in[4];
    const float* beta  = (const float*)d_in[5];
    const float* rmean = (const float*)d_in[6];
    const float* rvar  = (const float*)d_in[7];
    const float* gW0   = (const float*)d_in[8];
    const float* gb0   = (const float*)d_in[9];
    const float* gW1   = (const float*)d_in[10];
    const float* gb1   = (const float*)d_in[11];
    const float* gW2   = (const float*)d_in[12];
    const float* gb2   = (const float*)d_in[13];
    const float* gateW = (const float*)d_in[14];
    const float* gateb = (const float*)d_in[15];
    const float* pW1   = (const float*)d_in[16];
    const float* pb1   = (const float*)d_in[17];
    const float* pW2   = (const float*)d_in[18];
    const float* pb2   = (const float*)d_in[19];
    const float* cW    = (const float*)d_in[20];
    const float* cb    = (const float*)d_in[21];

    const int N = in_sizes[0] / 128;
    const int E = in_sizes[1] / 2;
    const int* e_src = edge;
    const int* e_dst = edge + E;

    char* ws = (char*)d_ws;
    size_t o = 0;
    auto alloc = [&](size_t bytes) {
        void* p = ws + o;
        o += (bytes + 15) & ~(size_t)15;
        return p;
    };
    int* deg       = (int*)alloc((size_t)N * 4);
    int* excl      = (int*)alloc((size_t)N * 4);
    int* partials  = (int*)alloc(512 * 4);
    int* row_start = (int*)alloc(((size_t)N + 1) * 4);
    int* cursor    = (int*)alloc((size_t)N * 4);
    int* csr_src   = (int*)alloc((size_t)E * 4);
    float* dinv    = (float*)alloc((size_t)N * 4);
    float* h_mlp   = (float*)alloc((size_t)N * 64 * 4);
    ushort_t* hwA  = (ushort_t*)alloc((size_t)N * 64 * 2);
    ushort_t* hwB  = (ushort_t*)alloc((size_t)N * 64 * 2);

    float* logits = (float*)d_out;
    float* zproj  = (float*)d_out + N;

    const int nblkN  = (N + 255) / 256;
    const int nblkE  = (E + 255) / 256;
    const int nblkR  = (N + 3) / 4;
    const int aggBlk = 4096;
    const size_t lds0 = 4096 * 4;           // 16KB: sW only
    const size_t lds1 = (4096 + 2048) * 4;  // 24KB: sW + sW2

    hipMemsetAsync(deg, 0, (size_t)N * sizeof(int), stream);
    deg_kernel<<<nblkE, 256, 0, stream>>>(e_dst, E, deg);
    scanA<<<nblkN, 256, 0, stream>>>(deg, excl, partials, N);
    scanB<<<1, 512, 0, stream>>>(partials, nblkN);
    scanC<<<nblkN, 256, 0, stream>>>(excl, partials, deg, row_start, cursor, dinv, N, E);
    fill_csr<<<nblkE, 256, 0, stream>>>(e_src, e_dst, E, cursor, csr_src);

    gemm128_fused<<<nblkR, 256, 0, stream>>>(x, W1, b1, gamma, beta, rmean, rvar,
                                             gW0, dinv, h_mlp, hwA, N);

    agg_kernel<0><<<aggBlk, 256, lds0, stream>>>(hwA, row_start, csr_src, dinv, gb0,
                                                 gW1, nullptr, nullptr, nullptr,
                                                 nullptr, nullptr, nullptr, nullptr,
                                                 nullptr, nullptr, hwB, nullptr, nullptr, N);
    agg_kernel<0><<<aggBlk, 256, lds0, stream>>>(hwB, row_start, csr_src, dinv, gb1,
                                                 gW2, nullptr, nullptr, nullptr,
                                                 nullptr, nullptr, nullptr, nullptr,
                                                 nullptr, nullptr, hwA, nullptr, nullptr, N);
    agg_kernel<1><<<aggBlk, 256, lds1, stream>>>(hwA, row_start, csr_src, dinv, gb2,
                                                 nullptr, h_mlp, gateW, gateb,
                                                 pW1, pb1, pW2, pb2, cW, cb,
                                                 nullptr, logits, zproj, N);
}

// Round 5
// 508.608 us; speedup vs baseline: 2.6235x; 1.5354x over previous
//
#include <hip/hip_runtime.h>
#include <hip/hip_bf16.h>

// BiomarkerGNN: N=100000, E=1200000, F=128, HID=64, PROJ=32.
// Round 5: 4 nodes per wave (16 lanes x uint2 per row), GEMV epilogue via
// LDS (transposed + XOR-swizzled W, register-blocked over 4 nodes) instead
// of shuffle-broadcast. DS ops/node ~144 -> ~25. MODE0 LDS 20KB -> 8
// blocks/CU.
//
// Pipeline:
//   deg histogram -> scan -> CSR fill (by dst)
//   gemm128_fused: h_mlp(f32) = relu(BN(x@W1+b1)); hwA(bf16) = (x@gW0)*dinv
//   agg2<0>(hwA->hwB): hg=relu(dinv*(self+sum)+gb0); hwB=(hg@gW1)*dinv
//   agg2<0>(hwB->hwA): ... gb1, gW2
//   agg2<1>(hwA): hg2 + gate/fuse/projection/classifier -> logits, zproj

#define HID 64

typedef unsigned short ushort_t;
typedef unsigned int uint_t;

__device__ __forceinline__ float bflo(uint_t u) {
    union { unsigned u; float f; } c;
    c.u = u << 16;
    return c.f;
}
__device__ __forceinline__ float bfhi(uint_t u) {
    union { unsigned u; float f; } c;
    c.u = u & 0xFFFF0000u;
    return c.f;
}
__device__ __forceinline__ ushort_t f2bf(float f) {
    union { float f; unsigned u; } c;
    c.f = f;
    unsigned u = c.u;
    unsigned r = (u + 0x7FFFu + ((u >> 16) & 1u)) >> 16;  // RNE
    return (ushort_t)r;
}

__global__ __launch_bounds__(256) void deg_kernel(const int* __restrict__ dst, int E,
                                                  int* __restrict__ deg) {
    int e = blockIdx.x * 256 + threadIdx.x;
    if (e < E) atomicAdd(&deg[dst[e]], 1);
}

__global__ __launch_bounds__(256) void scanA(const int* __restrict__ deg,
                                             int* __restrict__ excl,
                                             int* __restrict__ partials, int N) {
    __shared__ int s[256];
    int t = threadIdx.x;
    int i = blockIdx.x * 256 + t;
    int v = (i < N) ? deg[i] : 0;
    s[t] = v;
    __syncthreads();
    for (int off = 1; off < 256; off <<= 1) {
        int u = (t >= off) ? s[t - off] : 0;
        __syncthreads();
        s[t] += u;
        __syncthreads();
    }
    if (i < N) excl[i] = s[t] - v;
    if (t == 255) partials[blockIdx.x] = s[255];
}

__global__ __launch_bounds__(512) void scanB(int* __restrict__ partials, int P) {
    __shared__ int s[512];
    int t = threadIdx.x;
    int v = (t < P) ? partials[t] : 0;
    s[t] = v;
    __syncthreads();
    for (int off = 1; off < 512; off <<= 1) {
        int u = (t >= off) ? s[t - off] : 0;
        __syncthreads();
        s[t] += u;
        __syncthreads();
    }
    if (t < P) partials[t] = s[t] - v;
}

__global__ __launch_bounds__(256) void scanC(const int* __restrict__ excl,
                                             const int* __restrict__ partials,
                                             const int* __restrict__ deg,
                                             int* __restrict__ row_start,
                                             int* __restrict__ cursor,
                                             float* __restrict__ dinv, int N, int E) {
    int i = blockIdx.x * 256 + threadIdx.x;
    if (i < N) {
        int rs = excl[i] + partials[blockIdx.x];
        row_start[i] = rs;
        cursor[i] = rs;
        dinv[i] = rsqrtf((float)deg[i] + 1.0f);
        if (i == 0) row_start[N] = E;
    }
}

__global__ __launch_bounds__(256) void fill_csr(const int* __restrict__ src,
                                                const int* __restrict__ dst, int E,
                                                int* __restrict__ cursor,
                                                int* __restrict__ csr_src) {
    int e = blockIdx.x * 256 + threadIdx.x;
    if (e < E) {
        int pos = atomicAdd(&cursor[dst[e]], 1);
        csr_src[pos] = src[e];
    }
}

__global__ __launch_bounds__(256) void gemm128_fused(
    const float* __restrict__ x,
    const float* __restrict__ W1, const float* __restrict__ b1,
    const float* __restrict__ gamma, const float* __restrict__ beta,
    const float* __restrict__ rmean, const float* __restrict__ rvar,
    const float* __restrict__ gW0,
    const float* __restrict__ dinv,
    float* __restrict__ h_mlp, ushort_t* __restrict__ hw_s, int N) {
    __shared__ float sx[4][128];
    int tid = threadIdx.x;
    int rblk = blockIdx.x * 4;
    for (int i = tid; i < 512; i += 256) {
        int r = i >> 7, k = i & 127;
        int row = rblk + r;
        sx[r][k] = (row < N) ? x[(size_t)row * 128 + k] : 0.0f;
    }
    __syncthreads();
    int r = tid >> 6, c = tid & 63;
    int row = rblk + r;
    if (row >= N) return;
    float acc1 = 0.f, acc2 = 0.f;
#pragma unroll 8
    for (int k = 0; k < 128; ++k) {
        float xv = sx[r][k];
        acc1 = fmaf(xv, W1[k * HID + c], acc1);
        acc2 = fmaf(xv, gW0[k * HID + c], acc2);
    }
    float h = (acc1 + b1[c] - rmean[c]) * rsqrtf(rvar[c] + 1e-5f) * gamma[c] + beta[c];
    h_mlp[(size_t)row * HID + c] = fmaxf(h, 0.f);
    hw_s[(size_t)row * HID + c] = f2bf(acc2 * dinv[row]);
}

// Stage a 64x64 f32 weight into LDS transposed + XOR-swizzled:
// sWT[c*64 + ((kq ^ (c&7))<<2 | (k&3))] = W[k*64+c], kq = k>>2.
// Read back (lane=c): float4 at sWT[c*64 + ((kq ^ (c&7))<<2)].
__device__ __forceinline__ void stageWT(float* sWT, const float* W, int tid) {
    for (int i = tid; i < 4096; i += 256) {
        int k = i >> 6, c = i & 63;
        sWT[c * 64 + ((((k >> 2) ^ (c & 7)) << 2) | (k & 3))] = W[i];
    }
}

// 4 dst nodes per wave. Group g = lane>>4 owns node pack*4+g; sub = lane&15
// holds cols 4sub..4sub+3 via uint2 (8B) row slices.
// MODE 0: hg = relu(dinv*(self+sum)+gb); out_bf = (hg @ Wn)*dinv
// MODE 1: head -> logits, zproj.
template <int MODE>
__global__ __launch_bounds__(256) void agg2(
    const ushort_t* __restrict__ hw_s, const int* __restrict__ row_start,
    const int* __restrict__ csr_src, const float* __restrict__ dinv,
    const float* __restrict__ gb,
    const float* __restrict__ Wn,
    const float* __restrict__ h_mlp,
    const float* __restrict__ gateW, const float* __restrict__ gateb,
    const float* __restrict__ pW1, const float* __restrict__ pb1,
    const float* __restrict__ pW2, const float* __restrict__ pb2,
    const float* __restrict__ cW, const float* __restrict__ cb,
    ushort_t* __restrict__ out_bf,
    float* __restrict__ logits, float* __restrict__ zproj, int N) {
    extern __shared__ float smem[];
    float* sWT  = smem;                                   // 64x64
    float* sW2T = smem + 4096;                            // MODE1: 32 cols x 64 k
    float* sbuf = smem + (MODE == 0 ? 4096 : 4096 + 2048);  // 4 waves x 256
    int tid = threadIdx.x, lane = tid & 63, wid = tid >> 6;
    float* shg = sbuf + wid * 256;

    if (MODE == 0) {
        stageWT(sWT, Wn, tid);
    } else {
        stageWT(sWT, pW1, tid);
        for (int i = tid; i < 2048; i += 256) {            // pW2 [64][32]
            int k = i >> 5, c = i & 31;
            sW2T[c * 64 + ((((k >> 2) ^ (c & 7)) << 2) | (k & 3))] = pW2[i];
        }
    }
    __syncthreads();

    int g = lane >> 4, sub = lane & 15;
    float4 gb4 = ((const float4*)gb)[sub];
    float gWa = 0.f, gWb = 0.f, pb1v = 0.f, pb2v = 0.f, cWv = 0.f, gb0v = 0.f, cb0v = 0.f;
    if (MODE == 1) {
        gWa = gateW[lane];
        gWb = gateW[64 + lane];
        pb1v = pb1[lane];
        pb2v = pb2[lane & 31];
        cWv = cW[lane];
        gb0v = gateb[0];
        cb0v = cb[0];
    }

    int npacks = (N + 3) >> 2;
    for (int pack = blockIdx.x * 4 + wid; pack < npacks; pack += gridDim.x * 4) {
        int d0 = pack * 4;
        int d = d0 + g;
        bool ok = d < N;
        int dd = ok ? d : N - 1;
        int rs = row_start[dd];
        int deg = ok ? (row_start[dd + 1] - rs) : 0;

        // self contribution (hw_s already carries one dinv factor)
        uint2 sv = ((const uint2*)(hw_s + (size_t)dd * HID))[sub];
        float ax, ay, az, aw;
        if (ok) { ax = bflo(sv.x); ay = bfhi(sv.x); az = bflo(sv.y); aw = bfhi(sv.y); }
        else    { ax = ay = az = aw = 0.f; }

        // wave-uniform loop bound = max degree over the 4 groups
        int dmax = deg;
        dmax = max(dmax, __shfl_xor(dmax, 16, 64));
        dmax = max(dmax, __shfl_xor(dmax, 32, 64));

        for (int base = 0; base < dmax; base += 16) {
            int idx = (base + sub < deg) ? csr_src[rs + base + sub] : 0;
            int m = dmax - base;
            if (m > 16) m = 16;
            for (int j = 0; j < m; j += 4) {
                int s0 = __shfl(idx, (g << 4) | (j + 0), 64);
                int s1 = __shfl(idx, (g << 4) | (j + 1), 64);
                int s2 = __shfl(idx, (g << 4) | (j + 2), 64);
                int s3 = __shfl(idx, (g << 4) | (j + 3), 64);
                bool v0 = base + j + 0 < deg, v1 = base + j + 1 < deg;
                bool v2 = base + j + 2 < deg, v3 = base + j + 3 < deg;
                uint2 g0 = ((const uint2*)(hw_s + (size_t)s0 * HID))[sub];
                uint2 g1 = ((const uint2*)(hw_s + (size_t)s1 * HID))[sub];
                uint2 g2 = ((const uint2*)(hw_s + (size_t)s2 * HID))[sub];
                uint2 g3 = ((const uint2*)(hw_s + (size_t)s3 * HID))[sub];
                if (v0) { ax += bflo(g0.x); ay += bfhi(g0.x); az += bflo(g0.y); aw += bfhi(g0.y); }
                if (v1) { ax += bflo(g1.x); ay += bfhi(g1.x); az += bflo(g1.y); aw += bfhi(g1.y); }
                if (v2) { ax += bflo(g2.x); ay += bfhi(g2.x); az += bflo(g2.y); aw += bfhi(g2.y); }
                if (v3) { ax += bflo(g3.x); ay += bfhi(g3.x); az += bflo(g3.y); aw += bfhi(g3.y); }
            }
        }

        float dv = dinv[dd];
        float h0 = fmaxf(fmaf(ax, dv, gb4.x), 0.f);
        float h1 = fmaxf(fmaf(ay, dv, gb4.y), 0.f);
        float h2 = fmaxf(fmaf(az, dv, gb4.z), 0.f);
        float h3 = fmaxf(fmaf(aw, dv, gb4.w), 0.f);
        if (!ok) { h0 = h1 = h2 = h3 = 0.f; }
        *(float4*)&shg[g * 64 + 4 * sub] = make_float4(h0, h1, h2, h3);
        // per-wave buffer: producer==consumer wave, compiler orders via lgkmcnt

        if (MODE == 0) {
            float a0 = 0.f, a1 = 0.f, a2 = 0.f, a3 = 0.f;
#pragma unroll 4
            for (int kq = 0; kq < 16; ++kq) {
                float4 w4 = *(const float4*)&sWT[lane * 64 + ((kq ^ (lane & 7)) << 2)];
                float4 x0 = *(const float4*)&shg[0 * 64 + kq * 4];
                float4 x1 = *(const float4*)&shg[1 * 64 + kq * 4];
                float4 x2 = *(const float4*)&shg[2 * 64 + kq * 4];
                float4 x3 = *(const float4*)&shg[3 * 64 + kq * 4];
                a0 = fmaf(x0.x, w4.x, a0); a0 = fmaf(x0.y, w4.y, a0);
                a0 = fmaf(x0.z, w4.z, a0); a0 = fmaf(x0.w, w4.w, a0);
                a1 = fmaf(x1.x, w4.x, a1); a1 = fmaf(x1.y, w4.y, a1);
                a1 = fmaf(x1.z, w4.z, a1); a1 = fmaf(x1.w, w4.w, a1);
                a2 = fmaf(x2.x, w4.x, a2); a2 = fmaf(x2.y, w4.y, a2);
                a2 = fmaf(x2.z, w4.z, a2); a2 = fmaf(x2.w, w4.w, a2);
                a3 = fmaf(x3.x, w4.x, a3); a3 = fmaf(x3.y, w4.y, a3);
                a3 = fmaf(x3.z, w4.z, a3); a3 = fmaf(x3.w, w4.w, a3);
            }
            float dv0 = __shfl(dv, 0, 64);
            float dv1 = __shfl(dv, 16, 64);
            float dv2 = __shfl(dv, 32, 64);
            float dv3 = __shfl(dv, 48, 64);
            if (d0 + 0 < N) out_bf[(size_t)(d0 + 0) * HID + lane] = f2bf(a0 * dv0);
            if (d0 + 1 < N) out_bf[(size_t)(d0 + 1) * HID + lane] = f2bf(a1 * dv1);
            if (d0 + 2 < N) out_bf[(size_t)(d0 + 2) * HID + lane] = f2bf(a2 * dv2);
            if (d0 + 3 < N) out_bf[(size_t)(d0 + 3) * HID + lane] = f2bf(a3 * dv3);
        } else {
            // ---- head for 4 nodes ----
            float hm0 = (d0 + 0 < N) ? h_mlp[(size_t)(d0 + 0) * HID + lane] : 0.f;
            float hm1 = (d0 + 1 < N) ? h_mlp[(size_t)(d0 + 1) * HID + lane] : 0.f;
            float hm2 = (d0 + 2 < N) ? h_mlp[(size_t)(d0 + 2) * HID + lane] : 0.f;
            float hm3 = (d0 + 3 < N) ? h_mlp[(size_t)(d0 + 3) * HID + lane] : 0.f;
            float hg0 = shg[0 * 64 + lane];
            float hg1 = shg[1 * 64 + lane];
            float hg2 = shg[2 * 64 + lane];
            float hg3 = shg[3 * 64 + lane];
            float p0 = fmaf(hm0, gWa, hg0 * gWb);
            float p1 = fmaf(hm1, gWa, hg1 * gWb);
            float p2 = fmaf(hm2, gWa, hg2 * gWb);
            float p3 = fmaf(hm3, gWa, hg3 * gWb);
#pragma unroll
            for (int mm = 32; mm >= 1; mm >>= 1) {
                p0 += __shfl_xor(p0, mm, 64);
                p1 += __shfl_xor(p1, mm, 64);
                p2 += __shfl_xor(p2, mm, 64);
                p3 += __shfl_xor(p3, mm, 64);
            }
            float gate0 = 1.f / (1.f + expf(-(p0 + gb0v)));
            float gate1 = 1.f / (1.f + expf(-(p1 + gb0v)));
            float gate2 = 1.f / (1.f + expf(-(p2 + gb0v)));
            float gate3 = 1.f / (1.f + expf(-(p3 + gb0v)));
            float hf0 = gate0 * hg0 + (1.f - gate0) * hm0;
            float hf1 = gate1 * hg1 + (1.f - gate1) * hm1;
            float hf2 = gate2 * hg2 + (1.f - gate2) * hm2;
            float hf3 = gate3 * hg3 + (1.f - gate3) * hm3;
            // overwrite shg with hf for the t-GEMV
            shg[0 * 64 + lane] = hf0;
            shg[1 * 64 + lane] = hf1;
            shg[2 * 64 + lane] = hf2;
            shg[3 * 64 + lane] = hf3;
            float t0 = 0.f, t1 = 0.f, t2 = 0.f, t3 = 0.f;
#pragma unroll 4
            for (int kq = 0; kq < 16; ++kq) {
                float4 w4 = *(const float4*)&sWT[lane * 64 + ((kq ^ (lane & 7)) << 2)];
                float4 x0 = *(const float4*)&shg[0 * 64 + kq * 4];
                float4 x1 = *(const float4*)&shg[1 * 64 + kq * 4];
                float4 x2 = *(const float4*)&shg[2 * 64 + kq * 4];
                float4 x3 = *(const float4*)&shg[3 * 64 + kq * 4];
                t0 = fmaf(x0.x, w4.x, t0); t0 = fmaf(x0.y, w4.y, t0);
                t0 = fmaf(x0.z, w4.z, t0); t0 = fmaf(x0.w, w4.w, t0);
                t1 = fmaf(x1.x, w4.x, t1); t1 = fmaf(x1.y, w4.y, t1);
                t1 = fmaf(x1.z, w4.z, t1); t1 = fmaf(x1.w, w4.w, t1);
                t2 = fmaf(x2.x, w4.x, t2); t2 = fmaf(x2.y, w4.y, t2);
                t2 = fmaf(x2.z, w4.z, t2); t2 = fmaf(x2.w, w4.w, t2);
                t3 = fmaf(x3.x, w4.x, t3); t3 = fmaf(x3.y, w4.y, t3);
                t3 = fmaf(x3.z, w4.z, t3); t3 = fmaf(x3.w, w4.w, t3);
            }
            t0 = fmaxf(t0 + pb1v, 0.f);
            t1 = fmaxf(t1 + pb1v, 0.f);
            t2 = fmaxf(t2 + pb1v, 0.f);
            t3 = fmaxf(t3 + pb1v, 0.f);
            // overwrite shg with t for the z-GEMV
            shg[0 * 64 + lane] = t0;
            shg[1 * 64 + lane] = t1;
            shg[2 * 64 + lane] = t2;
            shg[3 * 64 + lane] = t3;
            // z: 32 output cols, lane&31 = col, lane>>5 = k-half
            int c2 = lane & 31, hh = lane >> 5;
            float z0 = 0.f, z1 = 0.f, z2 = 0.f, z3 = 0.f;
#pragma unroll 4
            for (int kq8 = 0; kq8 < 8; ++kq8) {
                int kq = hh * 8 + kq8;
                float4 w4 = *(const float4*)&sW2T[c2 * 64 + ((kq ^ (c2 & 7)) << 2)];
                float4 x0 = *(const float4*)&shg[0 * 64 + kq * 4];
                float4 x1 = *(const float4*)&shg[1 * 64 + kq * 4];
                float4 x2 = *(const float4*)&shg[2 * 64 + kq * 4];
                float4 x3 = *(const float4*)&shg[3 * 64 + kq * 4];
                z0 = fmaf(x0.x, w4.x, z0); z0 = fmaf(x0.y, w4.y, z0);
                z0 = fmaf(x0.z, w4.z, z0); z0 = fmaf(x0.w, w4.w, z0);
                z1 = fmaf(x1.x, w4.x, z1); z1 = fmaf(x1.y, w4.y, z1);
                z1 = fmaf(x1.z, w4.z, z1); z1 = fmaf(x1.w, w4.w, z1);
                z2 = fmaf(x2.x, w4.x, z2); z2 = fmaf(x2.y, w4.y, z2);
                z2 = fmaf(x2.z, w4.z, z2); z2 = fmaf(x2.w, w4.w, z2);
                z3 = fmaf(x3.x, w4.x, z3); z3 = fmaf(x3.y, w4.y, z3);
                z3 = fmaf(x3.z, w4.z, z3); z3 = fmaf(x3.w, w4.w, z3);
            }
            z0 += __shfl_xor(z0, 32, 64);
            z1 += __shfl_xor(z1, 32, 64);
            z2 += __shfl_xor(z2, 32, 64);
            z3 += __shfl_xor(z3, 32, 64);
            if (lane < 32) {
                if (d0 + 0 < N) zproj[(size_t)(d0 + 0) * 32 + c2] = z0 + pb2v;
                if (d0 + 1 < N) zproj[(size_t)(d0 + 1) * 32 + c2] = z1 + pb2v;
                if (d0 + 2 < N) zproj[(size_t)(d0 + 2) * 32 + c2] = z2 + pb2v;
                if (d0 + 3 < N) zproj[(size_t)(d0 + 3) * 32 + c2] = z3 + pb2v;
            }
            float q0 = hf0 * cWv, q1 = hf1 * cWv, q2 = hf2 * cWv, q3 = hf3 * cWv;
#pragma unroll
            for (int mm = 32; mm >= 1; mm >>= 1) {
                q0 += __shfl_xor(q0, mm, 64);
                q1 += __shfl_xor(q1, mm, 64);
                q2 += __shfl_xor(q2, mm, 64);
                q3 += __shfl_xor(q3, mm, 64);
            }
            if (lane == 0) {
                if (d0 + 0 < N) logits[d0 + 0] = q0 + cb0v;
                if (d0 + 1 < N) logits[d0 + 1] = q1 + cb0v;
                if (d0 + 2 < N) logits[d0 + 2] = q2 + cb0v;
                if (d0 + 3 < N) logits[d0 + 3] = q3 + cb0v;
            }
        }
    }
}

extern "C" void kernel_launch(void* const* d_in, const int* in_sizes, int n_in,
                              void* d_out, int out_size, void* d_ws, size_t ws_size,
                              hipStream_t stream) {
    const float* x     = (const float*)d_in[0];
    const int*   edge  = (const int*)d_in[1];
    const float* W1    = (const float*)d_in[2];
    const float* b1    = (const float*)d_in[3];
    const float* gamma = (const float*)d_in[4];
    const float* beta  = (const float*)d_in[5];
    const float* rmean = (const float*)d_in[6];
    const float* rvar  = (const float*)d_in[7];
    const float* gW0   = (const float*)d_in[8];
    const float* gb0   = (const float*)d_in[9];
    const float* gW1   = (const float*)d_in[10];
    const float* gb1   = (const float*)d_in[11];
    const float* gW2   = (const float*)d_in[12];
    const float* gb2   = (const float*)d_in[13];
    const float* gateW = (const float*)d_in[14];
    const float* gateb = (const float*)d_in[15];
    const float* pW1   = (const float*)d_in[16];
    const float* pb1   = (const float*)d_in[17];
    const float* pW2   = (const float*)d_in[18];
    const float* pb2   = (const float*)d_in[19];
    const float* cW    = (const float*)d_in[20];
    const float* cb    = (const float*)d_in[21];

    const int N = in_sizes[0] / 128;
    const int E = in_sizes[1] / 2;
    const int* e_src = edge;
    const int* e_dst = edge + E;

    char* ws = (char*)d_ws;
    size_t o = 0;
    auto alloc = [&](size_t bytes) {
        void* p = ws + o;
        o += (bytes + 15) & ~(size_t)15;
        return p;
    };
    int* deg       = (int*)alloc((size_t)N * 4);
    int* excl      = (int*)alloc((size_t)N * 4);
    int* partials  = (int*)alloc(512 * 4);
    int* row_start = (int*)alloc(((size_t)N + 1) * 4);
    int* cursor    = (int*)alloc((size_t)N * 4);
    int* csr_src   = (int*)alloc((size_t)E * 4);
    float* dinv    = (float*)alloc((size_t)N * 4);
    float* h_mlp   = (float*)alloc((size_t)N * 64 * 4);
    ushort_t* hwA  = (ushort_t*)alloc((size_t)N * 64 * 2);
    ushort_t* hwB  = (ushort_t*)alloc((size_t)N * 64 * 2);

    float* logits = (float*)d_out;
    float* zproj  = (float*)d_out + N;

    const int nblkN = (N + 255) / 256;
    const int nblkE = (E + 255) / 256;
    const int nblkR = (N + 3) / 4;
    const int blk0  = 2048;                       // MODE0: 8 blocks/CU
    const int blk1  = 1280;                       // MODE1: 5 blocks/CU
    const size_t lds0 = (4096 + 4 * 256) * 4;             // 20 KB
    const size_t lds1 = (4096 + 2048 + 4 * 256) * 4;      // 28 KB

    hipMemsetAsync(deg, 0, (size_t)N * sizeof(int), stream);
    deg_kernel<<<nblkE, 256, 0, stream>>>(e_dst, E, deg);
    scanA<<<nblkN, 256, 0, stream>>>(deg, excl, partials, N);
    scanB<<<1, 512, 0, stream>>>(partials, nblkN);
    scanC<<<nblkN, 256, 0, stream>>>(excl, partials, deg, row_start, cursor, dinv, N, E);
    fill_csr<<<nblkE, 256, 0, stream>>>(e_src, e_dst, E, cursor, csr_src);

    gemm128_fused<<<nblkR, 256, 0, stream>>>(x, W1, b1, gamma, beta, rmean, rvar,
                                             gW0, dinv, h_mlp, hwA, N);

    agg2<0><<<blk0, 256, lds0, stream>>>(hwA, row_start, csr_src, dinv, gb0,
                                         gW1, nullptr, nullptr, nullptr,
                                         nullptr, nullptr, nullptr, nullptr,
                                         nullptr, nullptr, hwB, nullptr, nullptr, N);
    agg2<0><<<blk0, 256, lds0, stream>>>(hwB, row_start, csr_src, dinv, gb1,
                                         gW2, nullptr, nullptr, nullptr,
                                         nullptr, nullptr, nullptr, nullptr,
                                         nullptr, nullptr, hwA, nullptr, nullptr, N);
    agg2<1><<<blk1, 256, lds1, stream>>>(hwA, row_start, csr_src, dinv, gb2,
                                         nullptr, h_mlp, gateW, gateb,
                                         pW1, pb1, pW2, pb2, cW, cb,
                                         nullptr, logits, zproj, N);
}